// Round 2
// baseline (321.138 us; speedup 1.0000x reference)
//
#include <hip/hip_runtime.h>

#define EPS 1e-5f

typedef __attribute__((ext_vector_type(8))) short s16x8;
typedef __attribute__((ext_vector_type(4))) float f4;

__device__ __forceinline__ short f2bf(float f) {
  union { float f; unsigned u; } x; x.f = f;
  unsigned r = x.u + 0x7fffu + ((x.u >> 16) & 1u);
  return (short)(r >> 16);
}
__device__ __forceinline__ float bf2f(short s) {
  union { unsigned u; float f; } x; x.u = ((unsigned)(unsigned short)s) << 16;
  return x.f;
}
__device__ __forceinline__ void gll16(const short* g, short* l) {
  __builtin_amdgcn_global_load_lds((const __attribute__((address_space(1))) void*)g,
                                   (__attribute__((address_space(3))) void*)l, 16, 0, 0);
}

#define BAR() asm volatile("s_barrier" ::: "memory")
#define LGKM0() do { asm volatile("s_waitcnt lgkmcnt(0)" ::: "memory"); \
                     __builtin_amdgcn_sched_barrier(0); } while (0)

// ---------------------------------------------------------------------------
// prep: fused  x fp32->bf16 cast  +  Wqkv transpose-cast  +  Wo transpose-cast.
// ---------------------------------------------------------------------------
__global__ __launch_bounds__(256) void prep(
    const float* __restrict__ x, const float* __restrict__ Wqkv,
    const float* __restrict__ Wo,
    short* __restrict__ xb, short* __restrict__ WqkvT, short* __restrict__ WoT)
{
  __shared__ float tile[32][33];
  const int bid = blockIdx.x;
  if (bid < 8192) {
    const size_t i = ((size_t)bid * 256 + threadIdx.x) * 8;
    const float4* p = reinterpret_cast<const float4*>(x + i);
    float4 a = p[0], b = p[1];
    union { uint4 v; short s[8]; } o;
    o.s[0] = f2bf(a.x); o.s[1] = f2bf(a.y); o.s[2] = f2bf(a.z); o.s[3] = f2bf(a.w);
    o.s[4] = f2bf(b.x); o.s[5] = f2bf(b.y); o.s[6] = f2bf(b.z); o.s[7] = f2bf(b.w);
    *reinterpret_cast<uint4*>(xb + i) = o.v;
    return;
  }
  const float* W; short* WT; int K, N, t;
  if (bid < 11264) { W = Wqkv; WT = WqkvT; K = 1024; N = 3072; t = bid - 8192;  }
  else             { W = Wo;   WT = WoT;   K = 1024; N = 1024; t = bid - 11264; }
  const int nblk = N >> 5;
  const int n0 = (t % nblk) * 32, k0 = (t / nblk) * 32;
  const int tx = threadIdx.x & 31, ty = threadIdx.x >> 5;
  #pragma unroll
  for (int i = 0; i < 4; i++) {
    int r = ty + i * 8;
    tile[r][tx] = W[(size_t)(k0 + r) * N + n0 + tx];
  }
  __syncthreads();
  #pragma unroll
  for (int i = 0; i < 4; i++) {
    int r = ty + i * 8;
    WT[(size_t)(n0 + r) * K + k0 + tx] = f2bf(tile[tx][r]);
  }
}

// ---------------------------------------------------------------------------
// 8-phase 256x256 / BK=64 GEMM core (T2 swizzle + T3/T4 counted vmcnt + T5).
// ---------------------------------------------------------------------------
__device__ __forceinline__ void stage_slice(const short* __restrict__ G, short* dstbase,
                                            int row0, int kcol, int rowgrp, int panel, int lane) {
  short* dst = dstbase + panel * 8192 + rowgrp * 512;
  const short* src = G + (size_t)(row0 + rowgrp * 16 + (lane >> 2)) * 1024
                       + kcol + panel * 32 + (((lane & 3) << 3) ^ ((lane >> 5) << 4));
  gll16(src, dst);
}

template<bool STAGE>
__device__ __forceinline__ void ktile8p(
    const short* ldsAc, const short* ldsBc, short* ldsAn, short* ldsBn,
    const short* __restrict__ A, const short* __restrict__ BT,
    int m0, int n0, int knext,
    int w, int lane, int wm, int wn, int quad, int l16,
    f4 (&acc)[8][4])
{
  s16x8 bfr[4][2];
  const int co = (quad << 3) ^ ((l16 >> 3) << 4);   // swizzled k-offset (shorts)
  #pragma unroll
  for (int p = 0; p < 4; ++p) {
    s16x8 a00, a01, a10, a11;
    {
      const int r0 = (wm * 128 + p * 32 + l16) * 32;
      a00 = *reinterpret_cast<const s16x8*>(&ldsAc[r0 + co]);
      a01 = *reinterpret_cast<const s16x8*>(&ldsAc[8192 + r0 + co]);
      a10 = *reinterpret_cast<const s16x8*>(&ldsAc[r0 + 512 + co]);
      a11 = *reinterpret_cast<const s16x8*>(&ldsAc[8192 + r0 + 512 + co]);
    }
    if (p == 0) {
      #pragma unroll
      for (int nf = 0; nf < 4; ++nf) {
        const int rb = (wn * 64 + nf * 16 + l16) * 32;
        bfr[nf][0] = *reinterpret_cast<const s16x8*>(&ldsBc[rb + co]);
        bfr[nf][1] = *reinterpret_cast<const s16x8*>(&ldsBc[8192 + rb + co]);
      }
    }
    if (STAGE) {
      if (p == 0)      { stage_slice(BT, ldsBn, n0, knext, w,     0, lane); stage_slice(BT, ldsBn, n0, knext, w,     1, lane); }
      else if (p == 1) { stage_slice(BT, ldsBn, n0, knext, 8 + w, 0, lane); stage_slice(BT, ldsBn, n0, knext, 8 + w, 1, lane); }
      else if (p == 2) { const int rg = (w & 3) + ((w >> 2) << 3);
                         stage_slice(A, ldsAn, m0, knext, rg, 0, lane); stage_slice(A, ldsAn, m0, knext, rg, 1, lane); }
      else             { const int rg = 4 + (w & 3) + ((w >> 2) << 3);
                         stage_slice(A, ldsAn, m0, knext, rg, 0, lane); stage_slice(A, ldsAn, m0, knext, rg, 1, lane); }
    }
    BAR();
    LGKM0();
    __builtin_amdgcn_s_setprio(1);
    #pragma unroll
    for (int nf = 0; nf < 4; ++nf) {
      acc[2*p  ][nf] = __builtin_amdgcn_mfma_f32_16x16x32_bf16(a00, bfr[nf][0], acc[2*p  ][nf], 0, 0, 0);
      acc[2*p  ][nf] = __builtin_amdgcn_mfma_f32_16x16x32_bf16(a01, bfr[nf][1], acc[2*p  ][nf], 0, 0, 0);
      acc[2*p+1][nf] = __builtin_amdgcn_mfma_f32_16x16x32_bf16(a10, bfr[nf][0], acc[2*p+1][nf], 0, 0, 0);
      acc[2*p+1][nf] = __builtin_amdgcn_mfma_f32_16x16x32_bf16(a11, bfr[nf][1], acc[2*p+1][nf], 0, 0, 0);
    }
    __builtin_amdgcn_s_setprio(0);
    if (p == 1) {
      if (STAGE) asm volatile("s_waitcnt vmcnt(4)" ::: "memory");
      else       asm volatile("s_waitcnt vmcnt(0)" ::: "memory");
    }
    if (p == 3 && STAGE) asm volatile("s_waitcnt vmcnt(2)" ::: "memory");
    BAR();
  }
}

#define GEMM8P_PROLOGUE()                                                            \
  stage_slice(BT, Bb0, n0, 0, w,     0, lane); stage_slice(BT, Bb0, n0, 0, w,     1, lane); \
  stage_slice(BT, Bb0, n0, 0, 8 + w, 0, lane); stage_slice(BT, Bb0, n0, 0, 8 + w, 1, lane); \
  { const int rg = (w & 3) + ((w >> 2) << 3);                                        \
    stage_slice(A, Ab0, m0, 0, rg, 0, lane); stage_slice(A, Ab0, m0, 0, rg, 1, lane); } \
  { const int rg = 4 + (w & 3) + ((w >> 2) << 3);                                    \
    stage_slice(A, Ab0, m0, 0, rg, 0, lane); stage_slice(A, Ab0, m0, 0, rg, 1, lane); } \
  asm volatile("s_waitcnt vmcnt(2)" ::: "memory");                                   \
  BAR()

#define GEMM8P_MAINLOOP()                                                            \
  _Pragma("unroll 1")                                                                \
  for (int t = 0; t < 14; t += 2) {                                                  \
    ktile8p<true>(Ab0, Bb0, Ab1, Bb1, A, BT, m0, n0, (t + 1) << 6, w, lane, wm, wn, quad, l16, acc); \
    ktile8p<true>(Ab1, Bb1, Ab0, Bb0, A, BT, m0, n0, (t + 2) << 6, w, lane, wm, wn, quad, l16, acc); \
  }                                                                                  \
  ktile8p<true >(Ab0, Bb0, Ab1, Bb1, A, BT, m0, n0, 15 << 6, w, lane, wm, wn, quad, l16, acc); \
  ktile8p<false>(Ab1, Bb1, Ab0, Bb0, A, BT, m0, n0, 0,       w, lane, wm, wn, quad, l16, acc)

// GEMM1: xb(16384x1024) @ WqkvT^T(3072x1024) -> q/k/v scatter. 768 blocks x 512.
__global__ __launch_bounds__(512, 2) void gemm_qkv_8p(
    const short* __restrict__ A, const short* __restrict__ BT,
    short* __restrict__ qb, short* __restrict__ kb, short* __restrict__ vb)
{
  extern __shared__ __align__(16) short lds[];
  short* Ab0 = lds;           short* Ab1 = lds + 16384;
  short* Bb0 = lds + 32768;   short* Bb1 = lds + 49152;

  const int pid = blockIdx.x;                    // 768 = 8 XCD x 96
  const int wg = (pid & 7) * 96 + (pid >> 3);    // bijective XCD swizzle
  const int mb = wg / 12, nb = wg % 12;
  const int m0 = mb * 256, n0 = nb * 256;

  const int tid = threadIdx.x;
  const int w = tid >> 6, lane = tid & 63, quad = lane >> 4, l16 = lane & 15;
  const int wm = w >> 2, wn = w & 3;             // 2x4 wave grid, 128x64 per wave

  f4 acc[8][4];
  #pragma unroll
  for (int i = 0; i < 8; i++)
    #pragma unroll
    for (int j = 0; j < 4; j++) acc[i][j] = {0.f, 0.f, 0.f, 0.f};

  GEMM8P_PROLOGUE();
  GEMM8P_MAINLOOP();

  __syncthreads();
  short* st = lds + w * 1152;                    // 16 rows x stride 72
  const int j0 = n0 + wn * 64;
  const int sq = j0 >> 10;
  const int hh = (j0 >> 6) & 15;
  short* dbuf = (sq == 0) ? qb : (sq == 1) ? kb : vb;
  const int r2 = lane >> 3, c8 = (lane & 7) << 3;
  #pragma unroll
  for (int mf = 0; mf < 8; ++mf) {
    #pragma unroll
    for (int nf = 0; nf < 4; ++nf)
      #pragma unroll
      for (int r = 0; r < 4; ++r)
        st[(quad * 4 + r) * 72 + nf * 16 + l16] = f2bf(acc[mf][nf][r]);
    #pragma unroll
    for (int h2 = 0; h2 < 2; ++h2) {
      int rr = h2 * 8 + r2;
      int i = m0 + wm * 128 + mf * 16 + rr;
      int bb = i >> 12, ll = i & 4095;
      uint4 val = *reinterpret_cast<const uint4*>(&st[rr * 72 + c8]);
      *reinterpret_cast<uint4*>(&dbuf[(((size_t)(bb * 16 + hh)) * 4096 + ll) * 64 + c8]) = val;
    }
  }
}

// GEMM2: yb(16384x1024) @ WoT^T(1024x1024) -> out fp32. 256 blocks x 512.
__global__ __launch_bounds__(512, 2) void gemm_out_8p(
    const short* __restrict__ A, const short* __restrict__ BT, float* __restrict__ C)
{
  extern __shared__ __align__(16) short lds[];
  short* Ab0 = lds;           short* Ab1 = lds + 16384;
  short* Bb0 = lds + 32768;   short* Bb1 = lds + 49152;

  const int pid = blockIdx.x;                    // 256 = 8 XCD x 32
  const int wg = (pid & 7) * 32 + (pid >> 3);
  const int mb = wg >> 2, nb = wg & 3;
  const int m0 = mb * 256, n0 = nb * 256;

  const int tid = threadIdx.x;
  const int w = tid >> 6, lane = tid & 63, quad = lane >> 4, l16 = lane & 15;
  const int wm = w >> 2, wn = w & 3;

  f4 acc[8][4];
  #pragma unroll
  for (int i = 0; i < 8; i++)
    #pragma unroll
    for (int j = 0; j < 4; j++) acc[i][j] = {0.f, 0.f, 0.f, 0.f};

  GEMM8P_PROLOGUE();
  GEMM8P_MAINLOOP();

  #pragma unroll
  for (int mf = 0; mf < 8; ++mf)
    #pragma unroll
    for (int nf = 0; nf < 4; ++nf)
      #pragma unroll
      for (int r = 0; r < 4; ++r) {
        int i = m0 + wm * 128 + mf * 16 + quad * 4 + r;
        int j = n0 + wn * 64 + nf * 16 + l16;
        C[(size_t)i * 1024 + j] = acc[mf][nf][r];
      }
}

// ---------------------------------------------------------------------------
// GEMM1 v4 (fallback if 128KB dynamic LDS unavailable): m97 structure.
// ---------------------------------------------------------------------------
__global__ __launch_bounds__(256) void gemm_qkv_v4(
    const short* __restrict__ A, const short* __restrict__ BT,
    short* __restrict__ qb, short* __restrict__ kb, short* __restrict__ vb)
{
  __shared__ __align__(16) short lds[8192];
  short* As = lds;
  short* Bs = lds + 4096;

  const int p = blockIdx.x;
  const int slot = p >> 3;
  const int strip = (p & 7) + 8 * (slot / 24);
  const int nb = slot % 24;
  const int m0 = strip * 128, n0 = nb * 128;

  const int tid = threadIdx.x;
  const int w = tid >> 6, lane = tid & 63, quad = lane >> 4, l16 = lane & 15;
  const int wm = (w >> 1) << 6, wn = (w & 1) << 6;

  f4 acc[4][4];
  #pragma unroll
  for (int i = 0; i < 4; i++)
    #pragma unroll
    for (int j = 0; j < 4; j++) acc[i][j] = {0.f, 0.f, 0.f, 0.f};

  const int row = w * 32 + (lane >> 2), ofs = (lane & 3) << 3;

  for (int k0 = 0; k0 < 1024; k0 += 32) {
    __syncthreads();
    gll16(A + (size_t)(m0 + row) * 1024 + k0 + ofs, &As[(w * 32) * 32]);
    gll16(A + (size_t)(m0 + row + 16) * 1024 + k0 + ofs, &As[(w * 32 + 16) * 32]);
    gll16(BT + (size_t)(n0 + row) * 1024 + k0 + ofs, &Bs[(w * 32) * 32]);
    gll16(BT + (size_t)(n0 + row + 16) * 1024 + k0 + ofs, &Bs[(w * 32 + 16) * 32]);
    __syncthreads();
    s16x8 afr[4], bfr[4];
    #pragma unroll
    for (int t = 0; t < 4; t++)
      afr[t] = *reinterpret_cast<const s16x8*>(&As[(wm + t * 16 + l16) * 32 + quad * 8]);
    #pragma unroll
    for (int t = 0; t < 4; t++)
      bfr[t] = *reinterpret_cast<const s16x8*>(&Bs[(wn + t * 16 + l16) * 32 + quad * 8]);
    #pragma unroll
    for (int ti = 0; ti < 4; ti++)
      #pragma unroll
      for (int tj = 0; tj < 4; tj++)
        acc[ti][tj] = __builtin_amdgcn_mfma_f32_16x16x32_bf16(afr[ti], bfr[tj], acc[ti][tj], 0, 0, 0);
  }

  __syncthreads();
  short* st = &lds[w * 16 * 72];
  const int j0 = n0 + wn;
  const int sq = j0 >> 10;
  const int hh = (j0 >> 6) & 15;
  short* dbuf = (sq == 0) ? qb : (sq == 1) ? kb : vb;
  const int r2 = lane >> 3, c8 = (lane & 7) << 3;
  #pragma unroll
  for (int ti = 0; ti < 4; ti++) {
    #pragma unroll
    for (int tj = 0; tj < 4; tj++)
      #pragma unroll
      for (int r = 0; r < 4; r++)
        st[(quad * 4 + r) * 72 + tj * 16 + l16] = f2bf(acc[ti][tj][r]);
    #pragma unroll
    for (int h2 = 0; h2 < 2; h2++) {
      int rr = h2 * 8 + r2;
      int i = m0 + wm + ti * 16 + rr;
      int bb = i >> 12, ll = i & 4095;
      uint4 val = *reinterpret_cast<const uint4*>(&st[rr * 72 + c8]);
      *reinterpret_cast<uint4*>(&dbuf[(((size_t)(bb * 16 + hh)) * 4096 + ll) * 64 + c8]) = val;
    }
  }
}

// ---------------------------------------------------------------------------
// LayerNorm kernel (fallback path only; fast path fuses LN).
// ---------------------------------------------------------------------------
__global__ __launch_bounds__(256) void ln_k(short* __restrict__ kbuf)
{
  const int row = blockIdx.x * 4 + (threadIdx.x >> 6);
  const int lane = threadIdx.x & 63;
  const size_t idx = (size_t)row * 64 + lane;
  float v = bf2f(kbuf[idx]);
  float s = v, s2 = v * v;
  #pragma unroll
  for (int off = 32; off; off >>= 1) {
    s += __shfl_xor(s, off);
    s2 += __shfl_xor(s2, off);
  }
  float mean = s * (1.f / 64.f);
  float var = s2 * (1.f / 64.f) - mean * mean;
  float rstd = rsqrtf(var + EPS);
  kbuf[idx] = f2bf((v - mean) * rstd);
}

// ---------------------------------------------------------------------------
// Scan pass A: G[bh][c] = sum_t v[t,:] k_ln[t,:]^T with LN(k) fused.
// LDS transpose buffers use block-XOR swizzle: col-block b' = b ^ (((row>>4)&3)<<1)
// -> writes 2-way (free, was 8-way); b128 reads stay 16B-aligned, <=2-way.
// ---------------------------------------------------------------------------
__global__ __launch_bounds__(256) void chunk_outer(
    const short* __restrict__ kb, const short* __restrict__ vb,
    short* __restrict__ G)
{
  __shared__ __align__(16) short kT[64 * 72];
  __shared__ __align__(16) short vT[64 * 72];
  const int bh = blockIdx.x >> 6, c = blockIdx.x & 63;
  const int tid = threadIdx.x;
  const int w = tid >> 6, lane = tid & 63, quad = lane >> 4, l16 = lane & 15;
  const int srow = tid >> 2, sseg = (tid & 3) << 4;
  const size_t base = (size_t)bh * 262144 + (size_t)(c * 64 + srow) * 64 + sseg;
  // swizzled write offset: col = srow, row-group g = tid&3 (rows sseg+i)
  const int toff = ((((srow >> 3) ^ ((tid & 3) << 1)) & 7) << 3) + (srow & 7);

  {
    const float4* kp = reinterpret_cast<const float4*>(kb + base);
    union { float4 v[2]; short s[16]; } ku;
    ku.v[0] = kp[0]; ku.v[1] = kp[1];
    float kv[16]; float s = 0.f, s2 = 0.f;
    #pragma unroll
    for (int i = 0; i < 16; i++) { kv[i] = bf2f(ku.s[i]); s += kv[i]; s2 += kv[i] * kv[i]; }
    s += __shfl_xor(s, 1);  s2 += __shfl_xor(s2, 1);
    s += __shfl_xor(s, 2);  s2 += __shfl_xor(s2, 2);
    float mean = s * (1.f / 64.f);
    float var = s2 * (1.f / 64.f) - mean * mean;
    float rstd = rsqrtf(var + EPS);
    #pragma unroll
    for (int i = 0; i < 16; i++) kT[(sseg + i) * 72 + toff] = f2bf((kv[i] - mean) * rstd);
    const float4* vp = reinterpret_cast<const float4*>(vb + base);
    union { float4 v[2]; short s[16]; } vu;
    vu.v[0] = vp[0]; vu.v[1] = vp[1];
    #pragma unroll
    for (int i = 0; i < 16; i++) vT[(sseg + i) * 72 + toff] = vu.s[i];
  }
  __syncthreads();
  const int gsw = (w & 3) << 1;    // rows w*16+l16 -> group w
  s16x8 va0 = *reinterpret_cast<const s16x8*>(&vT[(w * 16 + l16) * 72 + ((quad ^ gsw) << 3)]);
  s16x8 va1 = *reinterpret_cast<const s16x8*>(&vT[(w * 16 + l16) * 72 + (((4 + quad) ^ gsw) << 3)]);
  short* Gc = G + ((size_t)blockIdx.x) * 4096;
  #pragma unroll
  for (int tj = 0; tj < 4; tj++) {
    const int gk = (tj & 3) << 1;
    s16x8 kb0 = *reinterpret_cast<const s16x8*>(&kT[(tj * 16 + l16) * 72 + ((quad ^ gk) << 3)]);
    s16x8 kb1 = *reinterpret_cast<const s16x8*>(&kT[(tj * 16 + l16) * 72 + (((4 + quad) ^ gk) << 3)]);
    f4 z = {0.f, 0.f, 0.f, 0.f};
    z = __builtin_amdgcn_mfma_f32_16x16x32_bf16(va0, kb0, z, 0, 0, 0);
    z = __builtin_amdgcn_mfma_f32_16x16x32_bf16(va1, kb1, z, 0, 0, 0);
    #pragma unroll
    for (int r = 0; r < 4; r++)
      Gc[(w * 16 + quad * 4 + r) * 64 + tj * 16 + l16] = f2bf(z[r]);
  }
}

// ---------------------------------------------------------------------------
// Scan pass B: in-place exclusive prefix over c. Software-pipelined: load c+1
// issues before store c (no alias stall on the serial chain).
// ---------------------------------------------------------------------------
__global__ __launch_bounds__(128) void prefix_S(short* __restrict__ G)
{
  const int bh = blockIdx.x >> 3, rg = blockIdx.x & 7;
  short* p = G + (size_t)bh * 262144 + rg * 512 + threadIdx.x * 4;
  float s0 = 0.f, s1 = 0.f, s2 = 0.f, s3 = 0.f;
  union U { uint2 v; short s[4]; };
  U cur; cur.v = *reinterpret_cast<const uint2*>(p);
  #pragma unroll 4
  for (int c = 0; c < 64; c++) {
    short* pc = p + (size_t)c * 4096;
    U nxt;
    if (c < 63) nxt.v = *reinterpret_cast<const uint2*>(pc + 4096);
    float g0 = bf2f(cur.s[0]), g1 = bf2f(cur.s[1]), g2 = bf2f(cur.s[2]), g3 = bf2f(cur.s[3]);
    U su;
    su.s[0] = f2bf(s0); su.s[1] = f2bf(s1); su.s[2] = f2bf(s2); su.s[3] = f2bf(s3);
    *reinterpret_cast<uint2*>(pc) = su.v;
    s0 += g0; s1 += g1; s2 += g2; s3 += g3;
    cur = nxt;
  }
}

// ---------------------------------------------------------------------------
// Scan pass C: y = tril(q k_ln^T) v + q S^T-contract, LN(k) fused in-reg.
// vT swizzled like chunk_outer; Ps swizzled with b' = b ^ (((t>>2)&3)<<1)
// (writer rows vary by quad*4 -> writes free, was 4-way).
// ---------------------------------------------------------------------------
__global__ __launch_bounds__(256) void chunk_out(
    const short* __restrict__ qb, const short* __restrict__ kb,
    const short* __restrict__ vb, const short* __restrict__ S,
    short* __restrict__ yb)
{
  __shared__ __align__(16) short vT[64 * 72];
  __shared__ __align__(16) short Ps[64 * 72];
  const int bh = blockIdx.x >> 6, c = blockIdx.x & 63;
  const int b = bh >> 4, h = bh & 15;
  const int tid = threadIdx.x;
  const int w = tid >> 6, lane = tid & 63, quad = lane >> 4, l16 = lane & 15;
  const int srow = tid >> 2, sseg = (tid & 3) << 4;
  const size_t base = (size_t)bh * 262144 + (size_t)c * 4096;
  const int toff = ((((srow >> 3) ^ ((tid & 3) << 1)) & 7) << 3) + (srow & 7);

  {
    const float4* vp = reinterpret_cast<const float4*>(vb + base + (size_t)srow * 64 + sseg);
    union { float4 v[2]; short s[16]; } vu;
    vu.v[0] = vp[0]; vu.v[1] = vp[1];
    #pragma unroll
    for (int i = 0; i < 16; i++) vT[(sseg + i) * 72 + toff] = vu.s[i];
  }
  s16x8 qa[4][2], kf[2], sf[2];
  #pragma unroll
  for (int ti = 0; ti < 4; ti++)
    #pragma unroll
    for (int kh = 0; kh < 2; kh++)
      qa[ti][kh] = *reinterpret_cast<const s16x8*>(
          qb + base + (size_t)(ti * 16 + l16) * 64 + kh * 32 + quad * 8);
  #pragma unroll
  for (int kh = 0; kh < 2; kh++) {
    kf[kh] = *reinterpret_cast<const s16x8*>(
        kb + base + (size_t)(w * 16 + l16) * 64 + kh * 32 + quad * 8);
    sf[kh] = *reinterpret_cast<const s16x8*>(
        S + base + (size_t)(w * 16 + l16) * 64 + kh * 32 + quad * 8);
  }
  { // fused LN of k row (w*16+l16): row spread across lanes ^16, ^32
    float kv[16]; float s = 0.f, s2 = 0.f;
    #pragma unroll
    for (int kh = 0; kh < 2; kh++)
      #pragma unroll
      for (int i = 0; i < 8; i++) {
        float f = bf2f(kf[kh][i]); kv[kh * 8 + i] = f; s += f; s2 += f * f;
      }
    s += __shfl_xor(s, 16);  s2 += __shfl_xor(s2, 16);
    s += __shfl_xor(s, 32);  s2 += __shfl_xor(s2, 32);
    float mean = s * (1.f / 64.f);
    float var = s2 * (1.f / 64.f) - mean * mean;
    float rstd = rsqrtf(var + EPS);
    #pragma unroll
    for (int kh = 0; kh < 2; kh++)
      #pragma unroll
      for (int i = 0; i < 8; i++)
        kf[kh][i] = f2bf((kv[kh * 8 + i] - mean) * rstd);
  }
  __syncthreads();
  // Ps write: row t = ti*16+quad*4+r, col s = w*16+l16; (t>>2)&3 == quad
  const int psoff = ((((w * 16 + l16) >> 3) ^ (quad << 1)) << 3) + (l16 & 7);
  #pragma unroll
  for (int ti = 0; ti < 4; ti++) {
    f4 z = {0.f, 0.f, 0.f, 0.f};
    z = __builtin_amdgcn_mfma_f32_16x16x32_bf16(qa[ti][0], kf[0], z, 0, 0, 0);
    z = __builtin_amdgcn_mfma_f32_16x16x32_bf16(qa[ti][1], kf[1], z, 0, 0, 0);
    #pragma unroll
    for (int r = 0; r < 4; r++) {
      int t = ti * 16 + quad * 4 + r;
      int s = w * 16 + l16;
      Ps[t * 72 + psoff] = (s <= t) ? f2bf(z[r]) : (short)0;
    }
  }
  __syncthreads();
  const int gsw = (w & 3) << 1;
  s16x8 vf0 = *reinterpret_cast<const s16x8*>(&vT[(w * 16 + l16) * 72 + ((quad ^ gsw) << 3)]);
  s16x8 vf1 = *reinterpret_cast<const s16x8*>(&vT[(w * 16 + l16) * 72 + (((4 + quad) ^ gsw) << 3)]);
  const int pf = ((l16 >> 2) & 3) << 1;
  #pragma unroll
  for (int ti = 0; ti < 4; ti++) {
    f4 z = {0.f, 0.f, 0.f, 0.f};
    s16x8 p0 = *reinterpret_cast<const s16x8*>(&Ps[(ti * 16 + l16) * 72 + ((quad ^ pf) << 3)]);
    s16x8 p1 = *reinterpret_cast<const s16x8*>(&Ps[(ti * 16 + l16) * 72 + (((4 + quad) ^ pf) << 3)]);
    z = __builtin_amdgcn_mfma_f32_16x16x32_bf16(p0, vf0, z, 0, 0, 0);
    z = __builtin_amdgcn_mfma_f32_16x16x32_bf16(p1, vf1, z, 0, 0, 0);
    z = __builtin_amdgcn_mfma_f32_16x16x32_bf16(qa[ti][0], sf[0], z, 0, 0, 0);
    z = __builtin_amdgcn_mfma_f32_16x16x32_bf16(qa[ti][1], sf[1], z, 0, 0, 0);
    #pragma unroll
    for (int r = 0; r < 4; r++) {
      int t = ti * 16 + quad * 4 + r;
      int d = w * 16 + l16;
      yb[(((size_t)b * 4096) + c * 64 + t) * 1024 + h * 64 + d] = f2bf(z[r]);
    }
  }
}

// ---------------------------------------------------------------------------
// GEMM2 v3 (fallback): out = y(bf16) @ WoT^T, m97 structure + XCD swizzle.
// ---------------------------------------------------------------------------
__global__ __launch_bounds__(256) void gemm_out_v3(
    const short* __restrict__ A, const short* __restrict__ BT, float* __restrict__ C)
{
  __shared__ __align__(16) short As[128 * 32];
  __shared__ __align__(16) short Bs[128 * 32];
  const int p = blockIdx.x;
  const int slot = p >> 3;
  const int strip = (p & 7) + 8 * (slot >> 3);
  const int nb = slot & 7;
  const int m0 = strip * 128, n0 = nb * 128;
  const int tid = threadIdx.x;
  const int w = tid >> 6, lane = tid & 63, quad = lane >> 4, l16 = lane & 15;
  const int wm = (w >> 1) << 6, wn = (w & 1) << 6;

  f4 acc[4][4];
  #pragma unroll
  for (int i = 0; i < 4; i++)
    #pragma unroll
    for (int j = 0; j < 4; j++) acc[i][j] = {0.f, 0.f, 0.f, 0.f};

  const int row = w * 32 + (lane >> 2), ofs = (lane & 3) << 3;

  for (int k0 = 0; k0 < 1024; k0 += 32) {
    __syncthreads();
    gll16(A + (size_t)(m0 + row) * 1024 + k0 + ofs, &As[(w * 32) * 32]);
    gll16(A + (size_t)(m0 + row + 16) * 1024 + k0 + ofs, &As[(w * 32 + 16) * 32]);
    gll16(BT + (size_t)(n0 + row) * 1024 + k0 + ofs, &Bs[(w * 32) * 32]);
    gll16(BT + (size_t)(n0 + row + 16) * 1024 + k0 + ofs, &Bs[(w * 32 + 16) * 32]);
    __syncthreads();
    s16x8 afr[4], bfr[4];
    #pragma unroll
    for (int t = 0; t < 4; t++)
      afr[t] = *reinterpret_cast<const s16x8*>(&As[(wm + t * 16 + l16) * 32 + quad * 8]);
    #pragma unroll
    for (int t = 0; t < 4; t++)
      bfr[t] = *reinterpret_cast<const s16x8*>(&Bs[(wn + t * 16 + l16) * 32 + quad * 8]);
    #pragma unroll
    for (int ti = 0; ti < 4; ti++)
      #pragma unroll
      for (int tj = 0; tj < 4; tj++)
        acc[ti][tj] = __builtin_amdgcn_mfma_f32_16x16x32_bf16(afr[ti], bfr[tj], acc[ti][tj], 0, 0, 0);
  }
  #pragma unroll
  for (int ti = 0; ti < 4; ti++)
    #pragma unroll
    for (int tj = 0; tj < 4; tj++)
      #pragma unroll
      for (int r = 0; r < 4; r++) {
        int i = m0 + wm + ti * 16 + quad * 4 + r;
        int j = n0 + wn + tj * 16 + l16;
        C[(size_t)i * 1024 + j] = acc[ti][tj][r];
      }
}

// ===========================================================================
// Fallback path (round-1 kernels) for small ws.
// ===========================================================================
__global__ __launch_bounds__(256) void gemm_qkv_r1(
    const float* __restrict__ A, const float* __restrict__ B,
    short* __restrict__ qb, short* __restrict__ kb, short* __restrict__ vb)
{
  __shared__ __align__(16) short As[128 * 40];
  __shared__ __align__(16) short Bs[128 * 40];
  const int n0 = blockIdx.x * 128;
  const int m0 = blockIdx.y * 128;
  const int tid = threadIdx.x;
  const int w = tid >> 6, lane = tid & 63, quad = lane >> 4, l16 = lane & 15;
  const int wm = (w >> 1) << 6, wn = (w & 1) << 6;
  f4 acc[4][4];
  #pragma unroll
  for (int i = 0; i < 4; i++)
    #pragma unroll
    for (int j = 0; j < 4; j++) acc[i][j] = {0.f, 0.f, 0.f, 0.f};
  const int arow = tid >> 1, aseg = (tid & 1) << 4;
  const int brow = tid >> 3, bseg = (tid & 7) << 4;
  for (int k0 = 0; k0 < 1024; k0 += 32) {
    __syncthreads();
    {
      const float4* ap = reinterpret_cast<const float4*>(A + (size_t)(m0 + arow) * 1024 + k0 + aseg);
      union { float4 v[4]; float f[16]; } af;
      af.v[0] = ap[0]; af.v[1] = ap[1]; af.v[2] = ap[2]; af.v[3] = ap[3];
      union { float4 v[2]; short s[16]; } ao;
      #pragma unroll
      for (int i = 0; i < 16; i++) ao.s[i] = f2bf(af.f[i]);
      float4* dst = reinterpret_cast<float4*>(&As[arow * 40 + aseg]);
      dst[0] = ao.v[0]; dst[1] = ao.v[1];
    }
    {
      const float4* bp = reinterpret_cast<const float4*>(B + (size_t)(k0 + brow) * 3072 + n0 + bseg);
      union { float4 v[4]; float f[16]; } bu;
      bu.v[0] = bp[0]; bu.v[1] = bp[1]; bu.v[2] = bp[2]; bu.v[3] = bp[3];
      #pragma unroll
      for (int i = 0; i < 16; i++) Bs[(bseg + i) * 40 + brow] = f2bf(bu.f[i]);
    }
    __syncthreads();
    s16x8 afr[4], bfr[4];
    #pragma unroll
    for (int t = 0; t < 4; t++)
      afr[t] = *reinterpret_cast<const s16x8*>(&As[(wm + t * 16 + l16) * 40 + quad * 8]);
    #pragma unroll
    for (int t = 0; t < 4; t++)
      bfr[t] = *reinterpret_cast<const s16x8*>(&Bs[(wn + t * 16 + l16) * 40 + quad * 8]);
    #pragma unroll
    for (int ti = 0; ti < 4; ti++)
      #pragma unroll
      for (int tj = 0; tj < 4; tj++)
        acc[ti][tj] = __builtin_amdgcn_mfma_f32_16x16x32_bf16(afr[ti], bfr[tj], acc[ti][tj], 0, 0, 0);
  }
  const int sq = n0 >> 10;
  short* dbuf = (sq == 0) ? qb : (sq == 1) ? kb : vb;
  #pragma unroll
  for (int ti = 0; ti < 4; ti++)
    #pragma unroll
    for (int tj = 0; tj < 4; tj++)
      #pragma unroll
      for (int r = 0; r < 4; r++) {
        int i = m0 + wm + ti * 16 + quad * 4 + r;
        int j = n0 + wn + tj * 16 + l16;
        int hh = (j >> 6) & 15, dd = j & 63;
        int bb = i >> 12, ll = i & 4095;
        dbuf[(((size_t)(bb * 16 + hh)) * 4096 + ll) * 64 + dd] = f2bf(acc[ti][tj][r]);
      }
}

__global__ __launch_bounds__(256) void scan_chunks_r1(
    const short* __restrict__ qb, const short* __restrict__ kb,
    const short* __restrict__ vb, short* __restrict__ yb)
{
  __shared__ __align__(16) short qs[64 * 72];
  __shared__ __align__(16) short ks[64 * 72];
  __shared__ __align__(16) short kT[64 * 72];
  __shared__ __align__(16) short vT[64 * 72];
  __shared__ __align__(16) short Sb[64 * 72];
  __shared__ __align__(16) short Ps[64 * 72];
  const int bh = blockIdx.x;
  const int b = bh >> 4, h = bh & 15;
  const int tid = threadIdx.x;
  const int w = tid >> 6, lane = tid & 63, quad = lane >> 4, l16 = lane & 15;
  const int srow = tid >> 2, sseg = (tid & 3) << 4;
  const size_t base = (size_t)bh * 4096 * 64;
  f4 accS[4];
  #pragma unroll
  for (int i = 0; i < 4; i++) accS[i] = {0.f, 0.f, 0.f, 0.f};
  for (int c = 0; c < 64; c++) {
    __syncthreads();
    {
      size_t g = base + ((size_t)(c * 64 + srow)) * 64 + sseg;
      const float4* qp = reinterpret_cast<const float4*>(qb + g);
      float4 q0 = qp[0], q1 = qp[1];
      *reinterpret_cast<float4*>(&qs[srow * 72 + sseg]) = q0;
      *reinterpret_cast<float4*>(&qs[srow * 72 + sseg + 8]) = q1;
      const float4* kp = reinterpret_cast<const float4*>(kb + g);
      union { float4 v[2]; short s[16]; } ku;
      ku.v[0] = kp[0]; ku.v[1] = kp[1];
      *reinterpret_cast<float4*>(&ks[srow * 72 + sseg]) = ku.v[0];
      *reinterpret_cast<float4*>(&ks[srow * 72 + sseg + 8]) = ku.v[1];
      #pragma unroll
      for (int i = 0; i < 16; i++) kT[(sseg + i) * 72 + srow] = ku.s[i];
      const float4* vp = reinterpret_cast<const float4*>(vb + g);
      union { float4 v[2]; short s[16]; } vu;
      vu.v[0] = vp[0]; vu.v[1] = vp[1];
      #pragma unroll
      for (int i = 0; i < 16; i++) vT[(sseg + i) * 72 + srow] = vu.s[i];
    }
    #pragma unroll
    for (int ti = 0; ti < 4; ti++)
      #pragma unroll
      for (int r = 0; r < 4; r++)
        Sb[(ti * 16 + quad * 4 + r) * 72 + w * 16 + l16] = f2bf(accS[ti][r]);
    __syncthreads();
    s16x8 qa[4][2];
    #pragma unroll
    for (int ti = 0; ti < 4; ti++)
      #pragma unroll
      for (int kh = 0; kh < 2; kh++)
        qa[ti][kh] = *reinterpret_cast<const s16x8*>(&qs[(ti * 16 + l16) * 72 + kh * 32 + quad * 8]);
    s16x8 kf[2];
    #pragma unroll
    for (int kh = 0; kh < 2; kh++)
      kf[kh] = *reinterpret_cast<const s16x8*>(&ks[(w * 16 + l16) * 72 + kh * 32 + quad * 8]);
    #pragma unroll
    for (int ti = 0; ti < 4; ti++) {
      f4 z = {0.f, 0.f, 0.f, 0.f};
      z = __builtin_amdgcn_mfma_f32_16x16x32_bf16(qa[ti][0], kf[0], z, 0, 0, 0);
      z = __builtin_amdgcn_mfma_f32_16x16x32_bf16(qa[ti][1], kf[1], z, 0, 0, 0);
      #pragma unroll
      for (int r = 0; r < 4; r++) {
        int t = ti * 16 + quad * 4 + r;
        int s = w * 16 + l16;
        Ps[t * 72 + s] = (s <= t) ? f2bf(z[r]) : (short)0;
      }
    }
    __syncthreads();
    s16x8 vf[2], sf[2];
    #pragma unroll
    for (int kh = 0; kh < 2; kh++) {
      vf[kh] = *reinterpret_cast<const s16x8*>(&vT[(w * 16 + l16) * 72 + kh * 32 + quad * 8]);
      sf[kh] = *reinterpret_cast<const s16x8*>(&Sb[(w * 16 + l16) * 72 + kh * 32 + quad * 8]);
    }
    #pragma unroll
    for (int ti = 0; ti < 4; ti++) {
      f4 z = {0.f, 0.f, 0.f, 0.f};
      s16x8 p0 = *reinterpret_cast<const s16x8*>(&Ps[(ti * 16 + l16) * 72 + quad * 8]);
      s16x8 p1 = *reinterpret_cast<const s16x8*>(&Ps[(ti * 16 + l16) * 72 + 32 + quad * 8]);
      z = __builtin_amdgcn_mfma_f32_16x16x32_bf16(p0, vf[0], z, 0, 0, 0);
      z = __builtin_amdgcn_mfma_f32_16x16x32_bf16(p1, vf[1], z, 0, 0, 0);
      z = __builtin_amdgcn_mfma_f32_16x16x32_bf16(qa[ti][0], sf[0], z, 0, 0, 0);
      z = __builtin_amdgcn_mfma_f32_16x16x32_bf16(qa[ti][1], sf[1], z, 0, 0, 0);
      #pragma unroll
      for (int r = 0; r < 4; r++) {
        int t = ti * 16 + quad * 4 + r;
        int d = w * 16 + l16;
        yb[(((size_t)b * 4096) + c * 64 + t) * 1024 + h * 64 + d] = f2bf(z[r]);
      }
    }
    s16x8 ku0 = *reinterpret_cast<const s16x8*>(&kT[(w * 16 + l16) * 72 + quad * 8]);
    s16x8 ku1 = *reinterpret_cast<const s16x8*>(&kT[(w * 16 + l16) * 72 + 32 + quad * 8]);
    #pragma unroll
    for (int ti = 0; ti < 4; ti++) {
      s16x8 va0 = *reinterpret_cast<const s16x8*>(&vT[(ti * 16 + l16) * 72 + quad * 8]);
      s16x8 va1 = *reinterpret_cast<const s16x8*>(&vT[(ti * 16 + l16) * 72 + 32 + quad * 8]);
      accS[ti] = __builtin_amdgcn_mfma_f32_16x16x32_bf16(va0, ku0, accS[ti], 0, 0, 0);
      accS[ti] = __builtin_amdgcn_mfma_f32_16x16x32_bf16(va1, ku1, accS[ti], 0, 0, 0);
    }
  }
}

__global__ __launch_bounds__(256) void gemm_out_r1(
    const short* __restrict__ A, const float* __restrict__ B, float* __restrict__ C)
{
  __shared__ __align__(16) short As[128 * 40];
  __shared__ __align__(16) short Bs[128 * 40];
  const int n0 = blockIdx.x * 128;
  const int m0 = blockIdx.y * 128;
  const int tid = threadIdx.x;
  const int w = tid >> 6, lane = tid & 63, quad = lane >> 4, l16 = lane & 15;
  const int wm = (w >> 1) << 6, wn = (w & 1) << 6;
  f4 acc[4][4];
  #pragma unroll
  for (int i = 0; i < 4; i++)
    #pragma unroll
    for (int j = 0; j < 4; j++) acc[i][j] = {0.f, 0.f, 0.f, 0.f};
  const int arow = tid >> 1, aseg = (tid & 1) << 4;
  const int brow = tid >> 3, bseg = (tid & 7) << 4;
  for (int k0 = 0; k0 < 1024; k0 += 32) {
    __syncthreads();
    {
      const float4* ap = reinterpret_cast<const float4*>(A + (size_t)(m0 + arow) * 1024 + k0 + aseg);
      float4 a0 = ap[0], a1 = ap[1];
      float4* dst = reinterpret_cast<float4*>(&As[arow * 40 + aseg]);
      dst[0] = a0; dst[1] = a1;
    }
    {
      const float4* bp = reinterpret_cast<const float4*>(B + (size_t)(k0 + brow) * 1024 + n0 + bseg);
      union { float4 v[4]; float f[16]; } bu;
      bu.v[0] = bp[0]; bu.v[1] = bp[1]; bu.v[2] = bp[2]; bu.v[3] = bp[3];
      #pragma unroll
      for (int i = 0; i < 16; i++) Bs[(bseg + i) * 40 + brow] = f2bf(bu.f[i]);
    }
    __syncthreads();
    s16x8 afr[4], bfr[4];
    #pragma unroll
    for (int t = 0; t < 4; t++)
      afr[t] = *reinterpret_cast<const s16x8*>(&As[(wm + t * 16 + l16) * 40 + quad * 8]);
    #pragma unroll
    for (int t = 0; t < 4; t++)
      bfr[t] = *reinterpret_cast<const s16x8*>(&Bs[(wn + t * 16 + l16) * 40 + quad * 8]);
    #pragma unroll
    for (int ti = 0; ti < 4; ti++)
      #pragma unroll
      for (int tj = 0; tj < 4; tj++)
        acc[ti][tj] = __builtin_amdgcn_mfma_f32_16x16x32_bf16(afr[ti], bfr[tj], acc[ti][tj], 0, 0, 0);
  }
  #pragma unroll
  for (int ti = 0; ti < 4; ti++)
    #pragma unroll
    for (int tj = 0; tj < 4; tj++)
      #pragma unroll
      for (int r = 0; r < 4; r++) {
        int i = m0 + wm + ti * 16 + quad * 4 + r;
        int j = n0 + wn + tj * 16 + l16;
        C[(size_t)i * 1024 + j] = acc[ti][tj][r];
      }
}

extern "C" void kernel_launch(void* const* d_in, const int* in_sizes, int n_in,
                              void* d_out, int out_size, void* d_ws, size_t ws_size,
                              hipStream_t stream) {
  const float* x    = (const float*)d_in[0];   // (4,4096,1024) fp32
  const float* Wqkv = (const float*)d_in[1];   // (1024,3072) fp32
  const float* Wo   = (const float*)d_in[2];   // (1024,1024) fp32
  float* out = (float*)d_out;                  // (4,4096,1024) fp32

  short* qb = (short*)d_ws;                    // 32 MB each region
  short* kb = qb + (size_t)16777216;
  short* vb = kb + (size_t)16777216;
  short* yb = vb + (size_t)16777216;

  const size_t NEED = 176160768;  // 168 MB fast-path footprint
  if (ws_size >= NEED) {
    short* Gs    = yb + (size_t)16777216;      // 32 MB: xb, then G/S (in-place)
    short* WqkvT = Gs + (size_t)16777216;      // 6 MB
    short* WoT   = WqkvT + (size_t)3145728;    // 2 MB
    short* xb    = Gs;                          // overlay: dead before chunk_outer

    // 128 KiB dynamic LDS for the 8-phase GEMMs; fall back to v4/v3 if denied.
    static int use8p = -1;
    if (use8p < 0) {
      hipError_t e1 = hipFuncSetAttribute((const void*)gemm_qkv_8p,
          hipFuncAttributeMaxDynamicSharedMemorySize, 131072);
      hipError_t e2 = hipFuncSetAttribute((const void*)gemm_out_8p,
          hipFuncAttributeMaxDynamicSharedMemorySize, 131072);
      use8p = (e1 == hipSuccess && e2 == hipSuccess) ? 1 : 0;
    }

    prep          <<<dim3(12288),   256, 0, stream>>>(x, Wqkv, Wo, xb, WqkvT, WoT);
    if (use8p)
      gemm_qkv_8p <<<dim3(768),     512, 131072, stream>>>(xb, WqkvT, qb, kb, vb);
    else
      gemm_qkv_v4 <<<dim3(3072),    256, 0, stream>>>(xb, WqkvT, qb, kb, vb);
    chunk_outer   <<<dim3(4096),    256, 0, stream>>>(kb, vb, Gs);
    prefix_S      <<<dim3(512),     128, 0, stream>>>(Gs);
    chunk_out     <<<dim3(4096),    256, 0, stream>>>(qb, kb, vb, Gs, yb);
    if (use8p)
      gemm_out_8p <<<dim3(256),     512, 131072, stream>>>(yb, WoT, out);
    else
      gemm_out_v3 <<<dim3(1024),    256, 0, stream>>>(yb, WoT, out);
  } else {
    gemm_qkv_r1   <<<dim3(24, 128), 256, 0, stream>>>(x, Wqkv, qb, kb, vb);
    ln_k          <<<dim3(65536),   256, 0, stream>>>(kb);
    scan_chunks_r1<<<dim3(64),      256, 0, stream>>>(qb, kb, vb, yb);
    gemm_out_r1   <<<dim3(8, 128),  256, 0, stream>>>(yb, Wo, out);
  }
}

// Round 3
// 300.369 us; speedup vs baseline: 1.0691x; 1.0691x over previous
//
#include <hip/hip_runtime.h>

#define EPS 1e-5f

typedef __attribute__((ext_vector_type(8))) short s16x8;
typedef __attribute__((ext_vector_type(4))) float f4;

__device__ __forceinline__ short f2bf(float f) {
  union { float f; unsigned u; } x; x.f = f;
  unsigned r = x.u + 0x7fffu + ((x.u >> 16) & 1u);
  return (short)(r >> 16);
}
__device__ __forceinline__ float bf2f(short s) {
  union { unsigned u; float f; } x; x.u = ((unsigned)(unsigned short)s) << 16;
  return x.f;
}
__device__ __forceinline__ void gll16(const short* g, short* l) {
  __builtin_amdgcn_global_load_lds((const __attribute__((address_space(1))) void*)g,
                                   (__attribute__((address_space(3))) void*)l, 16, 0, 0);
}

#define BAR() asm volatile("s_barrier" ::: "memory")
#define LGKM0() do { asm volatile("s_waitcnt lgkmcnt(0)" ::: "memory"); \
                     __builtin_amdgcn_sched_barrier(0); } while (0)

// ---------------------------------------------------------------------------
// prep: fused  x fp32->bf16 cast  +  Wqkv transpose-cast  +  Wo transpose-cast.
// ---------------------------------------------------------------------------
__global__ __launch_bounds__(256) void prep(
    const float* __restrict__ x, const float* __restrict__ Wqkv,
    const float* __restrict__ Wo,
    short* __restrict__ xb, short* __restrict__ WqkvT, short* __restrict__ WoT)
{
  __shared__ float tile[32][33];
  const int bid = blockIdx.x;
  if (bid < 8192) {
    const size_t i = ((size_t)bid * 256 + threadIdx.x) * 8;
    const float4* p = reinterpret_cast<const float4*>(x + i);
    float4 a = p[0], b = p[1];
    union { uint4 v; short s[8]; } o;
    o.s[0] = f2bf(a.x); o.s[1] = f2bf(a.y); o.s[2] = f2bf(a.z); o.s[3] = f2bf(a.w);
    o.s[4] = f2bf(b.x); o.s[5] = f2bf(b.y); o.s[6] = f2bf(b.z); o.s[7] = f2bf(b.w);
    *reinterpret_cast<uint4*>(xb + i) = o.v;
    return;
  }
  const float* W; short* WT; int K, N, t;
  if (bid < 11264) { W = Wqkv; WT = WqkvT; K = 1024; N = 3072; t = bid - 8192;  }
  else             { W = Wo;   WT = WoT;   K = 1024; N = 1024; t = bid - 11264; }
  const int nblk = N >> 5;
  const int n0 = (t % nblk) * 32, k0 = (t / nblk) * 32;
  const int tx = threadIdx.x & 31, ty = threadIdx.x >> 5;
  #pragma unroll
  for (int i = 0; i < 4; i++) {
    int r = ty + i * 8;
    tile[r][tx] = W[(size_t)(k0 + r) * N + n0 + tx];
  }
  __syncthreads();
  #pragma unroll
  for (int i = 0; i < 4; i++) {
    int r = ty + i * 8;
    WT[(size_t)(n0 + r) * K + k0 + tx] = f2bf(tile[tx][r]);
  }
}

// ---------------------------------------------------------------------------
// 8-phase 256x256 / BK=64 GEMM core (T2 swizzle + T3/T4 counted vmcnt + T5).
// ---------------------------------------------------------------------------
__device__ __forceinline__ void stage_slice(const short* __restrict__ G, short* dstbase,
                                            int row0, int kcol, int rowgrp, int panel, int lane) {
  short* dst = dstbase + panel * 8192 + rowgrp * 512;
  const short* src = G + (size_t)(row0 + rowgrp * 16 + (lane >> 2)) * 1024
                       + kcol + panel * 32 + (((lane & 3) << 3) ^ ((lane >> 5) << 4));
  gll16(src, dst);
}

template<bool STAGE>
__device__ __forceinline__ void ktile8p(
    const short* ldsAc, const short* ldsBc, short* ldsAn, short* ldsBn,
    const short* __restrict__ A, const short* __restrict__ BT,
    int m0, int n0, int knext,
    int w, int lane, int wm, int wn, int quad, int l16,
    f4 (&acc)[8][4])
{
  s16x8 bfr[4][2];
  const int co = (quad << 3) ^ ((l16 >> 3) << 4);   // swizzled k-offset (shorts)
  #pragma unroll
  for (int p = 0; p < 4; ++p) {
    s16x8 a00, a01, a10, a11;
    {
      const int r0 = (wm * 128 + p * 32 + l16) * 32;
      a00 = *reinterpret_cast<const s16x8*>(&ldsAc[r0 + co]);
      a01 = *reinterpret_cast<const s16x8*>(&ldsAc[8192 + r0 + co]);
      a10 = *reinterpret_cast<const s16x8*>(&ldsAc[r0 + 512 + co]);
      a11 = *reinterpret_cast<const s16x8*>(&ldsAc[8192 + r0 + 512 + co]);
    }
    if (p == 0) {
      #pragma unroll
      for (int nf = 0; nf < 4; ++nf) {
        const int rb = (wn * 64 + nf * 16 + l16) * 32;
        bfr[nf][0] = *reinterpret_cast<const s16x8*>(&ldsBc[rb + co]);
        bfr[nf][1] = *reinterpret_cast<const s16x8*>(&ldsBc[8192 + rb + co]);
      }
    }
    if (STAGE) {
      if (p == 0)      { stage_slice(BT, ldsBn, n0, knext, w,     0, lane); stage_slice(BT, ldsBn, n0, knext, w,     1, lane); }
      else if (p == 1) { stage_slice(BT, ldsBn, n0, knext, 8 + w, 0, lane); stage_slice(BT, ldsBn, n0, knext, 8 + w, 1, lane); }
      else if (p == 2) { const int rg = (w & 3) + ((w >> 2) << 3);
                         stage_slice(A, ldsAn, m0, knext, rg, 0, lane); stage_slice(A, ldsAn, m0, knext, rg, 1, lane); }
      else             { const int rg = 4 + (w & 3) + ((w >> 2) << 3);
                         stage_slice(A, ldsAn, m0, knext, rg, 0, lane); stage_slice(A, ldsAn, m0, knext, rg, 1, lane); }
    }
    BAR();
    LGKM0();
    __builtin_amdgcn_s_setprio(1);
    #pragma unroll
    for (int nf = 0; nf < 4; ++nf) {
      acc[2*p  ][nf] = __builtin_amdgcn_mfma_f32_16x16x32_bf16(a00, bfr[nf][0], acc[2*p  ][nf], 0, 0, 0);
      acc[2*p  ][nf] = __builtin_amdgcn_mfma_f32_16x16x32_bf16(a01, bfr[nf][1], acc[2*p  ][nf], 0, 0, 0);
      acc[2*p+1][nf] = __builtin_amdgcn_mfma_f32_16x16x32_bf16(a10, bfr[nf][0], acc[2*p+1][nf], 0, 0, 0);
      acc[2*p+1][nf] = __builtin_amdgcn_mfma_f32_16x16x32_bf16(a11, bfr[nf][1], acc[2*p+1][nf], 0, 0, 0);
    }
    __builtin_amdgcn_s_setprio(0);
    if (p == 1) {
      if (STAGE) asm volatile("s_waitcnt vmcnt(4)" ::: "memory");
      else       asm volatile("s_waitcnt vmcnt(0)" ::: "memory");
    }
    if (p == 3 && STAGE) asm volatile("s_waitcnt vmcnt(2)" ::: "memory");
    BAR();
  }
}

#define GEMM8P_PROLOGUE()                                                            \
  stage_slice(BT, Bb0, n0, 0, w,     0, lane); stage_slice(BT, Bb0, n0, 0, w,     1, lane); \
  stage_slice(BT, Bb0, n0, 0, 8 + w, 0, lane); stage_slice(BT, Bb0, n0, 0, 8 + w, 1, lane); \
  { const int rg = (w & 3) + ((w >> 2) << 3);                                        \
    stage_slice(A, Ab0, m0, 0, rg, 0, lane); stage_slice(A, Ab0, m0, 0, rg, 1, lane); } \
  { const int rg = 4 + (w & 3) + ((w >> 2) << 3);                                    \
    stage_slice(A, Ab0, m0, 0, rg, 0, lane); stage_slice(A, Ab0, m0, 0, rg, 1, lane); } \
  asm volatile("s_waitcnt vmcnt(2)" ::: "memory");                                   \
  BAR()

#define GEMM8P_MAINLOOP()                                                            \
  _Pragma("unroll 1")                                                                \
  for (int t = 0; t < 14; t += 2) {                                                  \
    ktile8p<true>(Ab0, Bb0, Ab1, Bb1, A, BT, m0, n0, (t + 1) << 6, w, lane, wm, wn, quad, l16, acc); \
    ktile8p<true>(Ab1, Bb1, Ab0, Bb0, A, BT, m0, n0, (t + 2) << 6, w, lane, wm, wn, quad, l16, acc); \
  }                                                                                  \
  ktile8p<true >(Ab0, Bb0, Ab1, Bb1, A, BT, m0, n0, 15 << 6, w, lane, wm, wn, quad, l16, acc); \
  ktile8p<false>(Ab1, Bb1, Ab0, Bb0, A, BT, m0, n0, 0,       w, lane, wm, wn, quad, l16, acc)

// GEMM1: xb(16384x1024) @ WqkvT^T(3072x1024) -> q/k/v scatter. 768 blocks x 512.
__global__ __launch_bounds__(512, 2) void gemm_qkv_8p(
    const short* __restrict__ A, const short* __restrict__ BT,
    short* __restrict__ qb, short* __restrict__ kb, short* __restrict__ vb)
{
  extern __shared__ __align__(16) short lds[];
  short* Ab0 = lds;           short* Ab1 = lds + 16384;
  short* Bb0 = lds + 32768;   short* Bb1 = lds + 49152;

  const int pid = blockIdx.x;                    // 768 = 8 XCD x 96
  const int wg = (pid & 7) * 96 + (pid >> 3);    // bijective XCD swizzle
  const int mb = wg / 12, nb = wg % 12;
  const int m0 = mb * 256, n0 = nb * 256;

  const int tid = threadIdx.x;
  const int w = tid >> 6, lane = tid & 63, quad = lane >> 4, l16 = lane & 15;
  const int wm = w >> 2, wn = w & 3;             // 2x4 wave grid, 128x64 per wave

  f4 acc[8][4];
  #pragma unroll
  for (int i = 0; i < 8; i++)
    #pragma unroll
    for (int j = 0; j < 4; j++) acc[i][j] = {0.f, 0.f, 0.f, 0.f};

  GEMM8P_PROLOGUE();
  GEMM8P_MAINLOOP();

  __syncthreads();
  short* st = lds + w * 1152;                    // 16 rows x stride 72
  const int j0 = n0 + wn * 64;
  const int sq = j0 >> 10;
  const int hh = (j0 >> 6) & 15;
  short* dbuf = (sq == 0) ? qb : (sq == 1) ? kb : vb;
  const int r2 = lane >> 3, c8 = (lane & 7) << 3;
  #pragma unroll
  for (int mf = 0; mf < 8; ++mf) {
    #pragma unroll
    for (int nf = 0; nf < 4; ++nf)
      #pragma unroll
      for (int r = 0; r < 4; ++r)
        st[(quad * 4 + r) * 72 + nf * 16 + l16] = f2bf(acc[mf][nf][r]);
    #pragma unroll
    for (int h2 = 0; h2 < 2; ++h2) {
      int rr = h2 * 8 + r2;
      int i = m0 + wm * 128 + mf * 16 + rr;
      int bb = i >> 12, ll = i & 4095;
      uint4 val = *reinterpret_cast<const uint4*>(&st[rr * 72 + c8]);
      *reinterpret_cast<uint4*>(&dbuf[(((size_t)(bb * 16 + hh)) * 4096 + ll) * 64 + c8]) = val;
    }
  }
}

// GEMM2: yb(16384x1024) @ WoT^T(1024x1024) -> out fp32. 256 blocks x 512.
__global__ __launch_bounds__(512, 2) void gemm_out_8p(
    const short* __restrict__ A, const short* __restrict__ BT, float* __restrict__ C)
{
  extern __shared__ __align__(16) short lds[];
  short* Ab0 = lds;           short* Ab1 = lds + 16384;
  short* Bb0 = lds + 32768;   short* Bb1 = lds + 49152;

  const int pid = blockIdx.x;                    // 256 = 8 XCD x 32
  const int wg = (pid & 7) * 32 + (pid >> 3);
  const int mb = wg >> 2, nb = wg & 3;
  const int m0 = mb * 256, n0 = nb * 256;

  const int tid = threadIdx.x;
  const int w = tid >> 6, lane = tid & 63, quad = lane >> 4, l16 = lane & 15;
  const int wm = w >> 2, wn = w & 3;

  f4 acc[8][4];
  #pragma unroll
  for (int i = 0; i < 8; i++)
    #pragma unroll
    for (int j = 0; j < 4; j++) acc[i][j] = {0.f, 0.f, 0.f, 0.f};

  GEMM8P_PROLOGUE();
  GEMM8P_MAINLOOP();

  #pragma unroll
  for (int mf = 0; mf < 8; ++mf)
    #pragma unroll
    for (int nf = 0; nf < 4; ++nf)
      #pragma unroll
      for (int r = 0; r < 4; ++r) {
        int i = m0 + wm * 128 + mf * 16 + quad * 4 + r;
        int j = n0 + wn * 64 + nf * 16 + l16;
        C[(size_t)i * 1024 + j] = acc[mf][nf][r];
      }
}

// ---------------------------------------------------------------------------
// GEMM1 v4 (fallback if 128KB dynamic LDS unavailable): m97 structure.
// ---------------------------------------------------------------------------
__global__ __launch_bounds__(256) void gemm_qkv_v4(
    const short* __restrict__ A, const short* __restrict__ BT,
    short* __restrict__ qb, short* __restrict__ kb, short* __restrict__ vb)
{
  __shared__ __align__(16) short lds[8192];
  short* As = lds;
  short* Bs = lds + 4096;

  const int p = blockIdx.x;
  const int slot = p >> 3;
  const int strip = (p & 7) + 8 * (slot / 24);
  const int nb = slot % 24;
  const int m0 = strip * 128, n0 = nb * 128;

  const int tid = threadIdx.x;
  const int w = tid >> 6, lane = tid & 63, quad = lane >> 4, l16 = lane & 15;
  const int wm = (w >> 1) << 6, wn = (w & 1) << 6;

  f4 acc[4][4];
  #pragma unroll
  for (int i = 0; i < 4; i++)
    #pragma unroll
    for (int j = 0; j < 4; j++) acc[i][j] = {0.f, 0.f, 0.f, 0.f};

  const int row = w * 32 + (lane >> 2), ofs = (lane & 3) << 3;

  for (int k0 = 0; k0 < 1024; k0 += 32) {
    __syncthreads();
    gll16(A + (size_t)(m0 + row) * 1024 + k0 + ofs, &As[(w * 32) * 32]);
    gll16(A + (size_t)(m0 + row + 16) * 1024 + k0 + ofs, &As[(w * 32 + 16) * 32]);
    gll16(BT + (size_t)(n0 + row) * 1024 + k0 + ofs, &Bs[(w * 32) * 32]);
    gll16(BT + (size_t)(n0 + row + 16) * 1024 + k0 + ofs, &Bs[(w * 32 + 16) * 32]);
    __syncthreads();
    s16x8 afr[4], bfr[4];
    #pragma unroll
    for (int t = 0; t < 4; t++)
      afr[t] = *reinterpret_cast<const s16x8*>(&As[(wm + t * 16 + l16) * 32 + quad * 8]);
    #pragma unroll
    for (int t = 0; t < 4; t++)
      bfr[t] = *reinterpret_cast<const s16x8*>(&Bs[(wn + t * 16 + l16) * 32 + quad * 8]);
    #pragma unroll
    for (int ti = 0; ti < 4; ti++)
      #pragma unroll
      for (int tj = 0; tj < 4; tj++)
        acc[ti][tj] = __builtin_amdgcn_mfma_f32_16x16x32_bf16(afr[ti], bfr[tj], acc[ti][tj], 0, 0, 0);
  }

  __syncthreads();
  short* st = &lds[w * 16 * 72];
  const int j0 = n0 + wn;
  const int sq = j0 >> 10;
  const int hh = (j0 >> 6) & 15;
  short* dbuf = (sq == 0) ? qb : (sq == 1) ? kb : vb;
  const int r2 = lane >> 3, c8 = (lane & 7) << 3;
  #pragma unroll
  for (int ti = 0; ti < 4; ti++) {
    #pragma unroll
    for (int tj = 0; tj < 4; tj++)
      #pragma unroll
      for (int r = 0; r < 4; r++)
        st[(quad * 4 + r) * 72 + tj * 16 + l16] = f2bf(acc[ti][tj][r]);
    #pragma unroll
    for (int h2 = 0; h2 < 2; h2++) {
      int rr = h2 * 8 + r2;
      int i = m0 + wm + ti * 16 + rr;
      int bb = i >> 12, ll = i & 4095;
      uint4 val = *reinterpret_cast<const uint4*>(&st[rr * 72 + c8]);
      *reinterpret_cast<uint4*>(&dbuf[(((size_t)(bb * 16 + hh)) * 4096 + ll) * 64 + c8]) = val;
    }
  }
}

// ---------------------------------------------------------------------------
// LayerNorm kernel (fallback path only; fast path fuses LN).
// ---------------------------------------------------------------------------
__global__ __launch_bounds__(256) void ln_k(short* __restrict__ kbuf)
{
  const int row = blockIdx.x * 4 + (threadIdx.x >> 6);
  const int lane = threadIdx.x & 63;
  const size_t idx = (size_t)row * 64 + lane;
  float v = bf2f(kbuf[idx]);
  float s = v, s2 = v * v;
  #pragma unroll
  for (int off = 32; off; off >>= 1) {
    s += __shfl_xor(s, off);
    s2 += __shfl_xor(s2, off);
  }
  float mean = s * (1.f / 64.f);
  float var = s2 * (1.f / 64.f) - mean * mean;
  float rstd = rsqrtf(var + EPS);
  kbuf[idx] = f2bf((v - mean) * rstd);
}

// ---------------------------------------------------------------------------
// Macro-scan pass A: G[bh][mc] = sum over 256 rows of v^T k_ln (LN fused).
// Accumulates 4 sub-chunks of 64 in MFMA registers -> G is 8.4 MB (was 32).
// ---------------------------------------------------------------------------
__global__ __launch_bounds__(256) void macro_outer(
    const short* __restrict__ kb, const short* __restrict__ vb,
    short* __restrict__ G)
{
  __shared__ __align__(16) short kT[64 * 72];
  __shared__ __align__(16) short vT[64 * 72];
  const int bh = blockIdx.x >> 4, mc = blockIdx.x & 15;
  const int tid = threadIdx.x;
  const int w = tid >> 6, lane = tid & 63, quad = lane >> 4, l16 = lane & 15;
  const int srow = tid >> 2, sseg = (tid & 3) << 4;
  const int toff = ((((srow >> 3) ^ ((tid & 3) << 1)) & 7) << 3) + (srow & 7);
  const int gsw = (w & 3) << 1;

  f4 accG[4];
  #pragma unroll
  for (int tj = 0; tj < 4; tj++) accG[tj] = {0.f, 0.f, 0.f, 0.f};

  for (int j = 0; j < 4; ++j) {
    if (j) __syncthreads();
    const size_t base = (size_t)bh * 262144 + (size_t)((mc * 4 + j) * 64 + srow) * 64 + sseg;
    {
      const float4* kp = reinterpret_cast<const float4*>(kb + base);
      union { float4 v[2]; short s[16]; } ku;
      ku.v[0] = kp[0]; ku.v[1] = kp[1];
      float kv[16]; float s = 0.f, s2 = 0.f;
      #pragma unroll
      for (int i = 0; i < 16; i++) { kv[i] = bf2f(ku.s[i]); s += kv[i]; s2 += kv[i] * kv[i]; }
      s += __shfl_xor(s, 1);  s2 += __shfl_xor(s2, 1);
      s += __shfl_xor(s, 2);  s2 += __shfl_xor(s2, 2);
      float mean = s * (1.f / 64.f);
      float var = s2 * (1.f / 64.f) - mean * mean;
      float rstd = rsqrtf(var + EPS);
      #pragma unroll
      for (int i = 0; i < 16; i++) kT[(sseg + i) * 72 + toff] = f2bf((kv[i] - mean) * rstd);
      const float4* vp = reinterpret_cast<const float4*>(vb + base);
      union { float4 v[2]; short s[16]; } vu;
      vu.v[0] = vp[0]; vu.v[1] = vp[1];
      #pragma unroll
      for (int i = 0; i < 16; i++) vT[(sseg + i) * 72 + toff] = vu.s[i];
    }
    __syncthreads();
    s16x8 va0 = *reinterpret_cast<const s16x8*>(&vT[(w * 16 + l16) * 72 + ((quad ^ gsw) << 3)]);
    s16x8 va1 = *reinterpret_cast<const s16x8*>(&vT[(w * 16 + l16) * 72 + (((4 + quad) ^ gsw) << 3)]);
    #pragma unroll
    for (int tj = 0; tj < 4; tj++) {
      const int gk = tj << 1;
      s16x8 kb0 = *reinterpret_cast<const s16x8*>(&kT[(tj * 16 + l16) * 72 + ((quad ^ gk) << 3)]);
      s16x8 kb1 = *reinterpret_cast<const s16x8*>(&kT[(tj * 16 + l16) * 72 + (((4 + quad) ^ gk) << 3)]);
      accG[tj] = __builtin_amdgcn_mfma_f32_16x16x32_bf16(va0, kb0, accG[tj], 0, 0, 0);
      accG[tj] = __builtin_amdgcn_mfma_f32_16x16x32_bf16(va1, kb1, accG[tj], 0, 0, 0);
    }
  }
  short* Gc = G + (size_t)blockIdx.x * 4096;
  #pragma unroll
  for (int tj = 0; tj < 4; tj++)
    #pragma unroll
    for (int r = 0; r < 4; r++)
      Gc[(w * 16 + quad * 4 + r) * 64 + tj * 16 + l16] = f2bf(accG[tj][r]);
}

// ---------------------------------------------------------------------------
// Macro-scan pass B: in-place exclusive prefix over 16 macro-chunks (was 64).
// ---------------------------------------------------------------------------
__global__ __launch_bounds__(128) void prefix_S16(short* __restrict__ G)
{
  const int bh = blockIdx.x >> 3, rg = blockIdx.x & 7;
  short* p = G + (size_t)bh * 65536 + rg * 512 + threadIdx.x * 4;
  float s0 = 0.f, s1 = 0.f, s2 = 0.f, s3 = 0.f;
  union U { uint2 v; short s[4]; };
  U cur; cur.v = *reinterpret_cast<const uint2*>(p);
  #pragma unroll 4
  for (int mc = 0; mc < 16; mc++) {
    short* pc = p + (size_t)mc * 4096;
    U nxt; nxt.v = cur.v;
    if (mc < 15) nxt.v = *reinterpret_cast<const uint2*>(pc + 4096);
    float g0 = bf2f(cur.s[0]), g1 = bf2f(cur.s[1]), g2 = bf2f(cur.s[2]), g3 = bf2f(cur.s[3]);
    U su;
    su.s[0] = f2bf(s0); su.s[1] = f2bf(s1); su.s[2] = f2bf(s2); su.s[3] = f2bf(s3);
    *reinterpret_cast<uint2*>(pc) = su.v;
    s0 += g0; s1 += g1; s2 += g2; s3 += g3;
    cur = nxt;
  }
}

// ---------------------------------------------------------------------------
// Macro-scan pass C: per (bh, mc) block, sequential over 4 sub-chunks with
// S kept in fp32 registers (init from exclusive macro prefix). Per sub-chunk:
// y = tril(q k_ln^T) v + q S^T, then S += v^T k_ln (chunk_outer-style MFMA).
// LN computed once in the loader, shared by kf (row) and kT (transposed).
// ---------------------------------------------------------------------------
__global__ __launch_bounds__(256) void macro_out(
    const short* __restrict__ qb, const short* __restrict__ kb,
    const short* __restrict__ vb, const short* __restrict__ G,
    short* __restrict__ yb)
{
  __shared__ __align__(16) short ks[64 * 72];
  __shared__ __align__(16) short kT[64 * 72];
  __shared__ __align__(16) short vT[64 * 72];
  __shared__ __align__(16) short Sb[64 * 72];
  __shared__ __align__(16) short Ps[64 * 72];
  const int bh = blockIdx.x >> 4, mc = blockIdx.x & 15;
  const int b = bh >> 4, h = bh & 15;
  const int tid = threadIdx.x;
  const int w = tid >> 6, lane = tid & 63, quad = lane >> 4, l16 = lane & 15;
  const int srow = tid >> 2, sseg = (tid & 3) << 4;
  const int toff = ((((srow >> 3) ^ ((tid & 3) << 1)) & 7) << 3) + (srow & 7);
  const int gsw = (w & 3) << 1;
  const int rq2 = ((l16 >> 2) & 3) << 1;   // reader-row quad XOR (Ps/Sb)

  // init S from exclusive macro prefix (fp32 regs, chunk_outer C-layout)
  const short* Sg = G + (size_t)blockIdx.x * 4096;
  f4 accS[4];
  #pragma unroll
  for (int tj = 0; tj < 4; tj++)
    #pragma unroll
    for (int r = 0; r < 4; r++)
      accS[tj][r] = bf2f(Sg[(w * 16 + quad * 4 + r) * 64 + tj * 16 + l16]);

  for (int j = 0; j < 4; ++j) {
    const int c = mc * 4 + j;
    if (j) __syncthreads();
    // stage S (bf16) for this sub-chunk's q·S^T
    #pragma unroll
    for (int tj = 0; tj < 4; tj++) {
      const int eb = (tj << 1) + (l16 >> 3);
      const int sbc = (((eb ^ (quad << 1)) & 7) << 3) + (l16 & 7);
      #pragma unroll
      for (int r = 0; r < 4; r++)
        Sb[(w * 16 + quad * 4 + r) * 72 + sbc] = f2bf(accS[tj][r]);
    }
    // loader: k -> ks (row-major, LN) + kT (transposed, LN); v -> vT
    const size_t base = (size_t)bh * 262144 + (size_t)(c * 64 + srow) * 64 + sseg;
    {
      const float4* kp = reinterpret_cast<const float4*>(kb + base);
      union { float4 v[2]; short s[16]; } ku;
      ku.v[0] = kp[0]; ku.v[1] = kp[1];
      float kv[16]; float s = 0.f, s2 = 0.f;
      #pragma unroll
      for (int i = 0; i < 16; i++) { kv[i] = bf2f(ku.s[i]); s += kv[i]; s2 += kv[i] * kv[i]; }
      s += __shfl_xor(s, 1);  s2 += __shfl_xor(s2, 1);
      s += __shfl_xor(s, 2);  s2 += __shfl_xor(s2, 2);
      float mean = s * (1.f / 64.f);
      float var = s2 * (1.f / 64.f) - mean * mean;
      float rstd = rsqrtf(var + EPS);
      union { float4 v[2]; short s[16]; } ko;
      #pragma unroll
      for (int i = 0; i < 16; i++) ko.s[i] = f2bf((kv[i] - mean) * rstd);
      *reinterpret_cast<float4*>(&ks[srow * 72 + sseg]) = ko.v[0];
      *reinterpret_cast<float4*>(&ks[srow * 72 + sseg + 8]) = ko.v[1];
      #pragma unroll
      for (int i = 0; i < 16; i++) kT[(sseg + i) * 72 + toff] = ko.s[i];
      const float4* vp = reinterpret_cast<const float4*>(vb + base);
      union { float4 v[2]; short s[16]; } vu;
      vu.v[0] = vp[0]; vu.v[1] = vp[1];
      #pragma unroll
      for (int i = 0; i < 16; i++) vT[(sseg + i) * 72 + toff] = vu.s[i];
    }
    // q fragments from global (independent of LDS)
    s16x8 qa[4][2];
    const size_t qbase = (size_t)bh * 262144 + (size_t)c * 4096;
    #pragma unroll
    for (int ti = 0; ti < 4; ti++)
      #pragma unroll
      for (int kh = 0; kh < 2; kh++)
        qa[ti][kh] = *reinterpret_cast<const s16x8*>(
            qb + qbase + (size_t)(ti * 16 + l16) * 64 + kh * 32 + quad * 8);
    __syncthreads();
    // kf from ks (LN'd rows), sf from Sb
    s16x8 kf[2], sf[2];
    #pragma unroll
    for (int kh = 0; kh < 2; kh++) {
      kf[kh] = *reinterpret_cast<const s16x8*>(&ks[(w * 16 + l16) * 72 + kh * 32 + quad * 8]);
      sf[kh] = *reinterpret_cast<const s16x8*>(&Sb[(w * 16 + l16) * 72 + ((((kh << 2) + quad) ^ rq2) << 3)]);
    }
    // QK^T -> Ps (tril mask, swizzled)
    const int psoff = (((((w * 16 + l16) >> 3) ^ (quad << 1)) & 7) << 3) + (l16 & 7);
    #pragma unroll
    for (int ti = 0; ti < 4; ti++) {
      f4 z = {0.f, 0.f, 0.f, 0.f};
      z = __builtin_amdgcn_mfma_f32_16x16x32_bf16(qa[ti][0], kf[0], z, 0, 0, 0);
      z = __builtin_amdgcn_mfma_f32_16x16x32_bf16(qa[ti][1], kf[1], z, 0, 0, 0);
      #pragma unroll
      for (int r = 0; r < 4; r++) {
        int t = ti * 16 + quad * 4 + r;
        int s = w * 16 + l16;
        Ps[t * 72 + psoff] = (s <= t) ? f2bf(z[r]) : (short)0;
      }
    }
    __syncthreads();
    s16x8 vf0 = *reinterpret_cast<const s16x8*>(&vT[(w * 16 + l16) * 72 + ((quad ^ gsw) << 3)]);
    s16x8 vf1 = *reinterpret_cast<const s16x8*>(&vT[(w * 16 + l16) * 72 + (((4 + quad) ^ gsw) << 3)]);
    // y = Ps·v + q·S^T
    #pragma unroll
    for (int ti = 0; ti < 4; ti++) {
      f4 z = {0.f, 0.f, 0.f, 0.f};
      s16x8 p0 = *reinterpret_cast<const s16x8*>(&Ps[(ti * 16 + l16) * 72 + ((quad ^ rq2) << 3)]);
      s16x8 p1 = *reinterpret_cast<const s16x8*>(&Ps[(ti * 16 + l16) * 72 + (((4 + quad) ^ rq2) << 3)]);
      z = __builtin_amdgcn_mfma_f32_16x16x32_bf16(p0, vf0, z, 0, 0, 0);
      z = __builtin_amdgcn_mfma_f32_16x16x32_bf16(p1, vf1, z, 0, 0, 0);
      z = __builtin_amdgcn_mfma_f32_16x16x32_bf16(qa[ti][0], sf[0], z, 0, 0, 0);
      z = __builtin_amdgcn_mfma_f32_16x16x32_bf16(qa[ti][1], sf[1], z, 0, 0, 0);
      #pragma unroll
      for (int r = 0; r < 4; r++) {
        int t = ti * 16 + quad * 4 + r;
        int d = w * 16 + l16;
        yb[(((size_t)b * 4096) + c * 64 + t) * 1024 + h * 64 + d] = f2bf(z[r]);
      }
    }
    // S += v^T k_ln for this sub-chunk (same fragments as chunk_outer)
    #pragma unroll
    for (int tj = 0; tj < 4; tj++) {
      const int gk = tj << 1;
      s16x8 ub0 = *reinterpret_cast<const s16x8*>(&kT[(tj * 16 + l16) * 72 + ((quad ^ gk) << 3)]);
      s16x8 ub1 = *reinterpret_cast<const s16x8*>(&kT[(tj * 16 + l16) * 72 + (((4 + quad) ^ gk) << 3)]);
      accS[tj] = __builtin_amdgcn_mfma_f32_16x16x32_bf16(vf0, ub0, accS[tj], 0, 0, 0);
      accS[tj] = __builtin_amdgcn_mfma_f32_16x16x32_bf16(vf1, ub1, accS[tj], 0, 0, 0);
    }
  }
}

// ---------------------------------------------------------------------------
// GEMM2 v3 (fallback): out = y(bf16) @ WoT^T, m97 structure + XCD swizzle.
// ---------------------------------------------------------------------------
__global__ __launch_bounds__(256) void gemm_out_v3(
    const short* __restrict__ A, const short* __restrict__ BT, float* __restrict__ C)
{
  __shared__ __align__(16) short As[128 * 32];
  __shared__ __align__(16) short Bs[128 * 32];
  const int p = blockIdx.x;
  const int slot = p >> 3;
  const int strip = (p & 7) + 8 * (slot >> 3);
  const int nb = slot & 7;
  const int m0 = strip * 128, n0 = nb * 128;
  const int tid = threadIdx.x;
  const int w = tid >> 6, lane = tid & 63, quad = lane >> 4, l16 = lane & 15;
  const int wm = (w >> 1) << 6, wn = (w & 1) << 6;

  f4 acc[4][4];
  #pragma unroll
  for (int i = 0; i < 4; i++)
    #pragma unroll
    for (int j = 0; j < 4; j++) acc[i][j] = {0.f, 0.f, 0.f, 0.f};

  const int row = w * 32 + (lane >> 2), ofs = (lane & 3) << 3;

  for (int k0 = 0; k0 < 1024; k0 += 32) {
    __syncthreads();
    gll16(A + (size_t)(m0 + row) * 1024 + k0 + ofs, &As[(w * 32) * 32]);
    gll16(A + (size_t)(m0 + row + 16) * 1024 + k0 + ofs, &As[(w * 32 + 16) * 32]);
    gll16(BT + (size_t)(n0 + row) * 1024 + k0 + ofs, &Bs[(w * 32) * 32]);
    gll16(BT + (size_t)(n0 + row + 16) * 1024 + k0 + ofs, &Bs[(w * 32 + 16) * 32]);
    __syncthreads();
    s16x8 afr[4], bfr[4];
    #pragma unroll
    for (int t = 0; t < 4; t++)
      afr[t] = *reinterpret_cast<const s16x8*>(&As[(wm + t * 16 + l16) * 32 + quad * 8]);
    #pragma unroll
    for (int t = 0; t < 4; t++)
      bfr[t] = *reinterpret_cast<const s16x8*>(&Bs[(wn + t * 16 + l16) * 32 + quad * 8]);
    #pragma unroll
    for (int ti = 0; ti < 4; ti++)
      #pragma unroll
      for (int tj = 0; tj < 4; tj++)
        acc[ti][tj] = __builtin_amdgcn_mfma_f32_16x16x32_bf16(afr[ti], bfr[tj], acc[ti][tj], 0, 0, 0);
  }
  #pragma unroll
  for (int ti = 0; ti < 4; ti++)
    #pragma unroll
    for (int tj = 0; tj < 4; tj++)
      #pragma unroll
      for (int r = 0; r < 4; r++) {
        int i = m0 + wm + ti * 16 + quad * 4 + r;
        int j = n0 + wn + tj * 16 + l16;
        C[(size_t)i * 1024 + j] = acc[ti][tj][r];
      }
}

// ===========================================================================
// Fallback path (round-1 kernels) for small ws.
// ===========================================================================
__global__ __launch_bounds__(256) void gemm_qkv_r1(
    const float* __restrict__ A, const float* __restrict__ B,
    short* __restrict__ qb, short* __restrict__ kb, short* __restrict__ vb)
{
  __shared__ __align__(16) short As[128 * 40];
  __shared__ __align__(16) short Bs[128 * 40];
  const int n0 = blockIdx.x * 128;
  const int m0 = blockIdx.y * 128;
  const int tid = threadIdx.x;
  const int w = tid >> 6, lane = tid & 63, quad = lane >> 4, l16 = lane & 15;
  const int wm = (w >> 1) << 6, wn = (w & 1) << 6;
  f4 acc[4][4];
  #pragma unroll
  for (int i = 0; i < 4; i++)
    #pragma unroll
    for (int j = 0; j < 4; j++) acc[i][j] = {0.f, 0.f, 0.f, 0.f};
  const int arow = tid >> 1, aseg = (tid & 1) << 4;
  const int brow = tid >> 3, bseg = (tid & 7) << 4;
  for (int k0 = 0; k0 < 1024; k0 += 32) {
    __syncthreads();
    {
      const float4* ap = reinterpret_cast<const float4*>(A + (size_t)(m0 + arow) * 1024 + k0 + aseg);
      union { float4 v[4]; float f[16]; } af;
      af.v[0] = ap[0]; af.v[1] = ap[1]; af.v[2] = ap[2]; af.v[3] = ap[3];
      union { float4 v[2]; short s[16]; } ao;
      #pragma unroll
      for (int i = 0; i < 16; i++) ao.s[i] = f2bf(af.f[i]);
      float4* dst = reinterpret_cast<float4*>(&As[arow * 40 + aseg]);
      dst[0] = ao.v[0]; dst[1] = ao.v[1];
    }
    {
      const float4* bp = reinterpret_cast<const float4*>(B + (size_t)(k0 + brow) * 3072 + n0 + bseg);
      union { float4 v[4]; float f[16]; } bu;
      bu.v[0] = bp[0]; bu.v[1] = bp[1]; bu.v[2] = bp[2]; bu.v[3] = bp[3];
      #pragma unroll
      for (int i = 0; i < 16; i++) Bs[(bseg + i) * 40 + brow] = f2bf(bu.f[i]);
    }
    __syncthreads();
    s16x8 afr[4], bfr[4];
    #pragma unroll
    for (int t = 0; t < 4; t++)
      afr[t] = *reinterpret_cast<const s16x8*>(&As[(wm + t * 16 + l16) * 40 + quad * 8]);
    #pragma unroll
    for (int t = 0; t < 4; t++)
      bfr[t] = *reinterpret_cast<const s16x8*>(&Bs[(wn + t * 16 + l16) * 40 + quad * 8]);
    #pragma unroll
    for (int ti = 0; ti < 4; ti++)
      #pragma unroll
      for (int tj = 0; tj < 4; tj++)
        acc[ti][tj] = __builtin_amdgcn_mfma_f32_16x16x32_bf16(afr[ti], bfr[tj], acc[ti][tj], 0, 0, 0);
  }
  const int sq = n0 >> 10;
  short* dbuf = (sq == 0) ? qb : (sq == 1) ? kb : vb;
  #pragma unroll
  for (int ti = 0; ti < 4; ti++)
    #pragma unroll
    for (int tj = 0; tj < 4; tj++)
      #pragma unroll
      for (int r = 0; r < 4; r++) {
        int i = m0 + wm + ti * 16 + quad * 4 + r;
        int j = n0 + wn + tj * 16 + l16;
        int hh = (j >> 6) & 15, dd = j & 63;
        int bb = i >> 12, ll = i & 4095;
        dbuf[(((size_t)(bb * 16 + hh)) * 4096 + ll) * 64 + dd] = f2bf(acc[ti][tj][r]);
      }
}

__global__ __launch_bounds__(256) void scan_chunks_r1(
    const short* __restrict__ qb, const short* __restrict__ kb,
    const short* __restrict__ vb, short* __restrict__ yb)
{
  __shared__ __align__(16) short qs[64 * 72];
  __shared__ __align__(16) short ks[64 * 72];
  __shared__ __align__(16) short kT[64 * 72];
  __shared__ __align__(16) short vT[64 * 72];
  __shared__ __align__(16) short Sb[64 * 72];
  __shared__ __align__(16) short Ps[64 * 72];
  const int bh = blockIdx.x;
  const int b = bh >> 4, h = bh & 15;
  const int tid = threadIdx.x;
  const int w = tid >> 6, lane = tid & 63, quad = lane >> 4, l16 = lane & 15;
  const int srow = tid >> 2, sseg = (tid & 3) << 4;
  const size_t base = (size_t)bh * 4096 * 64;
  f4 accS[4];
  #pragma unroll
  for (int i = 0; i < 4; i++) accS[i] = {0.f, 0.f, 0.f, 0.f};
  for (int c = 0; c < 64; c++) {
    __syncthreads();
    {
      size_t g = base + ((size_t)(c * 64 + srow)) * 64 + sseg;
      const float4* qp = reinterpret_cast<const float4*>(qb + g);
      float4 q0 = qp[0], q1 = qp[1];
      *reinterpret_cast<float4*>(&qs[srow * 72 + sseg]) = q0;
      *reinterpret_cast<float4*>(&qs[srow * 72 + sseg + 8]) = q1;
      const float4* kp = reinterpret_cast<const float4*>(kb + g);
      union { float4 v[2]; short s[16]; } ku;
      ku.v[0] = kp[0]; ku.v[1] = kp[1];
      *reinterpret_cast<float4*>(&ks[srow * 72 + sseg]) = ku.v[0];
      *reinterpret_cast<float4*>(&ks[srow * 72 + sseg + 8]) = ku.v[1];
      #pragma unroll
      for (int i = 0; i < 16; i++) kT[(sseg + i) * 72 + srow] = ku.s[i];
      const float4* vp = reinterpret_cast<const float4*>(vb + g);
      union { float4 v[2]; short s[16]; } vu;
      vu.v[0] = vp[0]; vu.v[1] = vp[1];
      #pragma unroll
      for (int i = 0; i < 16; i++) vT[(sseg + i) * 72 + srow] = vu.s[i];
    }
    #pragma unroll
    for (int ti = 0; ti < 4; ti++)
      #pragma unroll
      for (int r = 0; r < 4; r++)
        Sb[(ti * 16 + quad * 4 + r) * 72 + w * 16 + l16] = f2bf(accS[ti][r]);
    __syncthreads();
    s16x8 qa[4][2];
    #pragma unroll
    for (int ti = 0; ti < 4; ti++)
      #pragma unroll
      for (int kh = 0; kh < 2; kh++)
        qa[ti][kh] = *reinterpret_cast<const s16x8*>(&qs[(ti * 16 + l16) * 72 + kh * 32 + quad * 8]);
    s16x8 kf[2];
    #pragma unroll
    for (int kh = 0; kh < 2; kh++)
      kf[kh] = *reinterpret_cast<const s16x8*>(&ks[(w * 16 + l16) * 72 + kh * 32 + quad * 8]);
    #pragma unroll
    for (int ti = 0; ti < 4; ti++) {
      f4 z = {0.f, 0.f, 0.f, 0.f};
      z = __builtin_amdgcn_mfma_f32_16x16x32_bf16(qa[ti][0], kf[0], z, 0, 0, 0);
      z = __builtin_amdgcn_mfma_f32_16x16x32_bf16(qa[ti][1], kf[1], z, 0, 0, 0);
      #pragma unroll
      for (int r = 0; r < 4; r++) {
        int t = ti * 16 + quad * 4 + r;
        int s = w * 16 + l16;
        Ps[t * 72 + s] = (s <= t) ? f2bf(z[r]) : (short)0;
      }
    }
    __syncthreads();
    s16x8 vf[2], sf[2];
    #pragma unroll
    for (int kh = 0; kh < 2; kh++) {
      vf[kh] = *reinterpret_cast<const s16x8*>(&vT[(w * 16 + l16) * 72 + kh * 32 + quad * 8]);
      sf[kh] = *reinterpret_cast<const s16x8*>(&Sb[(w * 16 + l16) * 72 + kh * 32 + quad * 8]);
    }
    #pragma unroll
    for (int ti = 0; ti < 4; ti++) {
      f4 z = {0.f, 0.f, 0.f, 0.f};
      s16x8 p0 = *reinterpret_cast<const s16x8*>(&Ps[(ti * 16 + l16) * 72 + quad * 8]);
      s16x8 p1 = *reinterpret_cast<const s16x8*>(&Ps[(ti * 16 + l16) * 72 + 32 + quad * 8]);
      z = __builtin_amdgcn_mfma_f32_16x16x32_bf16(p0, vf[0], z, 0, 0, 0);
      z = __builtin_amdgcn_mfma_f32_16x16x32_bf16(p1, vf[1], z, 0, 0, 0);
      z = __builtin_amdgcn_mfma_f32_16x16x32_bf16(qa[ti][0], sf[0], z, 0, 0, 0);
      z = __builtin_amdgcn_mfma_f32_16x16x32_bf16(qa[ti][1], sf[1], z, 0, 0, 0);
      #pragma unroll
      for (int r = 0; r < 4; r++) {
        int t = ti * 16 + quad * 4 + r;
        int d = w * 16 + l16;
        yb[(((size_t)b * 4096) + c * 64 + t) * 1024 + h * 64 + d] = f2bf(z[r]);
      }
    }
    s16x8 ku0 = *reinterpret_cast<const s16x8*>(&kT[(w * 16 + l16) * 72 + quad * 8]);
    s16x8 ku1 = *reinterpret_cast<const s16x8*>(&kT[(w * 16 + l16) * 72 + 32 + quad * 8]);
    #pragma unroll
    for (int ti = 0; ti < 4; ti++) {
      s16x8 va0 = *reinterpret_cast<const s16x8*>(&vT[(ti * 16 + l16) * 72 + quad * 8]);
      s16x8 va1 = *reinterpret_cast<const s16x8*>(&vT[(ti * 16 + l16) * 72 + 32 + quad * 8]);
      accS[ti] = __builtin_amdgcn_mfma_f32_16x16x32_bf16(va0, ku0, accS[ti], 0, 0, 0);
      accS[ti] = __builtin_amdgcn_mfma_f32_16x16x32_bf16(va1, ku1, accS[ti], 0, 0, 0);
    }
  }
}

__global__ __launch_bounds__(256) void gemm_out_r1(
    const short* __restrict__ A, const float* __restrict__ B, float* __restrict__ C)
{
  __shared__ __align__(16) short As[128 * 40];
  __shared__ __align__(16) short Bs[128 * 40];
  const int n0 = blockIdx.x * 128;
  const int m0 = blockIdx.y * 128;
  const int tid = threadIdx.x;
  const int w = tid >> 6, lane = tid & 63, quad = lane >> 4, l16 = lane & 15;
  const int wm = (w >> 1) << 6, wn = (w & 1) << 6;
  f4 acc[4][4];
  #pragma unroll
  for (int i = 0; i < 4; i++)
    #pragma unroll
    for (int j = 0; j < 4; j++) acc[i][j] = {0.f, 0.f, 0.f, 0.f};
  const int arow = tid >> 1, aseg = (tid & 1) << 4;
  const int brow = tid >> 3, bseg = (tid & 7) << 4;
  for (int k0 = 0; k0 < 1024; k0 += 32) {
    __syncthreads();
    {
      const float4* ap = reinterpret_cast<const float4*>(A + (size_t)(m0 + arow) * 1024 + k0 + aseg);
      float4 a0 = ap[0], a1 = ap[1];
      float4* dst = reinterpret_cast<float4*>(&As[arow * 40 + aseg]);
      dst[0] = a0; dst[1] = a1;
    }
    {
      const float4* bp = reinterpret_cast<const float4*>(B + (size_t)(k0 + brow) * 1024 + n0 + bseg);
      union { float4 v[4]; float f[16]; } bu;
      bu.v[0] = bp[0]; bu.v[1] = bp[1]; bu.v[2] = bp[2]; bu.v[3] = bp[3];
      #pragma unroll
      for (int i = 0; i < 16; i++) Bs[(bseg + i) * 40 + brow] = f2bf(bu.f[i]);
    }
    __syncthreads();
    s16x8 afr[4], bfr[4];
    #pragma unroll
    for (int t = 0; t < 4; t++)
      afr[t] = *reinterpret_cast<const s16x8*>(&As[(wm + t * 16 + l16) * 40 + quad * 8]);
    #pragma unroll
    for (int t = 0; t < 4; t++)
      bfr[t] = *reinterpret_cast<const s16x8*>(&Bs[(wn + t * 16 + l16) * 40 + quad * 8]);
    #pragma unroll
    for (int ti = 0; ti < 4; ti++)
      #pragma unroll
      for (int tj = 0; tj < 4; tj++)
        acc[ti][tj] = __builtin_amdgcn_mfma_f32_16x16x32_bf16(afr[ti], bfr[tj], acc[ti][tj], 0, 0, 0);
  }
  #pragma unroll
  for (int ti = 0; ti < 4; ti++)
    #pragma unroll
    for (int tj = 0; tj < 4; tj++)
      #pragma unroll
      for (int r = 0; r < 4; r++) {
        int i = m0 + wm + ti * 16 + quad * 4 + r;
        int j = n0 + wn + tj * 16 + l16;
        C[(size_t)i * 1024 + j] = acc[ti][tj][r];
      }
}

extern "C" void kernel_launch(void* const* d_in, const int* in_sizes, int n_in,
                              void* d_out, int out_size, void* d_ws, size_t ws_size,
                              hipStream_t stream) {
  const float* x    = (const float*)d_in[0];   // (4,4096,1024) fp32
  const float* Wqkv = (const float*)d_in[1];   // (1024,3072) fp32
  const float* Wo   = (const float*)d_in[2];   // (1024,1024) fp32
  float* out = (float*)d_out;                  // (4,4096,1024) fp32

  short* qb = (short*)d_ws;                    // 32 MB each region
  short* kb = qb + (size_t)16777216;
  short* vb = kb + (size_t)16777216;
  short* yb = vb + (size_t)16777216;

  const size_t NEED = 176160768;  // 168 MB fast-path footprint
  if (ws_size >= NEED) {
    short* Gs    = yb + (size_t)16777216;      // 32 MB region: xb, then G (8.4 MB, in-place)
    short* WqkvT = Gs + (size_t)16777216;      // 6 MB
    short* WoT   = WqkvT + (size_t)3145728;    // 2 MB
    short* xb    = Gs;                          // overlay: dead before macro_outer

    // 128 KiB dynamic LDS for the 8-phase GEMMs; fall back to v4/v3 if denied.
    static int use8p = -1;
    if (use8p < 0) {
      hipError_t e1 = hipFuncSetAttribute((const void*)gemm_qkv_8p,
          hipFuncAttributeMaxDynamicSharedMemorySize, 131072);
      hipError_t e2 = hipFuncSetAttribute((const void*)gemm_out_8p,
          hipFuncAttributeMaxDynamicSharedMemorySize, 131072);
      use8p = (e1 == hipSuccess && e2 == hipSuccess) ? 1 : 0;
    }

    prep          <<<dim3(12288),   256, 0, stream>>>(x, Wqkv, Wo, xb, WqkvT, WoT);
    if (use8p)
      gemm_qkv_8p <<<dim3(768),     512, 131072, stream>>>(xb, WqkvT, qb, kb, vb);
    else
      gemm_qkv_v4 <<<dim3(3072),    256, 0, stream>>>(xb, WqkvT, qb, kb, vb);
    macro_outer   <<<dim3(1024),    256, 0, stream>>>(kb, vb, Gs);
    prefix_S16    <<<dim3(512),     128, 0, stream>>>(Gs);
    macro_out     <<<dim3(1024),    256, 0, stream>>>(qb, kb, vb, Gs, yb);
    if (use8p)
      gemm_out_8p <<<dim3(256),     512, 131072, stream>>>(yb, WoT, out);
    else
      gemm_out_v3 <<<dim3(1024),    256, 0, stream>>>(yb, WoT, out);
  } else {
    gemm_qkv_r1   <<<dim3(24, 128), 256, 0, stream>>>(x, Wqkv, qb, kb, vb);
    ln_k          <<<dim3(65536),   256, 0, stream>>>(kb);
    scan_chunks_r1<<<dim3(64),      256, 0, stream>>>(qb, kb, vb, yb);
    gemm_out_r1   <<<dim3(8, 128),  256, 0, stream>>>(yb, Wo, out);
  }
}